// Round 2
// baseline (724.385 us; speedup 1.0000x reference)
//
#include <hip/hip_runtime.h>
#include <hip/hip_bf16.h>

typedef unsigned short u16;
typedef unsigned int u32;
typedef __bf16 bf16x8 __attribute__((ext_vector_type(8)));
typedef float f32x4 __attribute__((ext_vector_type(4)));

#define D 128
#define H 256
#define TM 64
#define THREADS 256
#define LN_EPS 1e-5f

__device__ __forceinline__ u32 f2bf(float f) {
    union { float f; u32 u; } v; v.f = f;
    return (v.u + 0x7FFFu + ((v.u >> 16) & 1u)) >> 16;   // RNE, low 16 bits valid
}

// ---------------------------------------------------------------------------
// Pack w1 [128x256], w2 [256x256], wo [256x128] (f32 row-major, K x N) into
// bf16 MFMA-fragment-contiguous blocks:
//   block b (per (coltile n0=16, ktile k0=32)): 512 bf16, layout
//   out[b*512 + l*8 + i] = W[(k0 + (l>>4)*8 + i) * N + n0 + (l&15)]
//   block id: b = (n0/16)*(K/32) + (k0/32)
// ---------------------------------------------------------------------------
__global__ void pack_weights(const float* __restrict__ w1,
                             const float* __restrict__ w2,
                             const float* __restrict__ wo,
                             u16* __restrict__ pw) {
    int tid = blockIdx.x * blockDim.x + threadIdx.x;
    const float* W; int K, NN, local;
    if (tid < 32768)       { W = w1; K = 128; NN = 256; local = tid; }
    else if (tid < 98304)  { W = w2; K = 256; NN = 256; local = tid - 32768; }
    else if (tid < 131072) { W = wo; K = 256; NN = 128; local = tid - 98304; }
    else return;
    int b = local >> 9, within = local & 511;
    int l = within >> 3, i = within & 7;
    int nbk = K >> 5;
    int n0 = (b / nbk) << 4, k0 = (b % nbk) << 5;
    int k = k0 + ((l >> 4) << 3) + i;
    int n = n0 + (l & 15);
    pw[tid] = (u16)f2bf(W[k * NN + n]);
}

__global__ void zero_out_kernel(float4* __restrict__ out, int n4) {
    int i = blockIdx.x * blockDim.x + threadIdx.x;
    if (i < n4) out[i] = float4{0.f, 0.f, 0.f, 0.f};
}

// ---------------------------------------------------------------------------
// Fused: LN1 -> GEMM1(+b1,ELU) -> LN2 -> GEMM2(+b2) -> gate -> GEMM3(+bo,*gate)
//        -> atomic scatter-add to out[node]
// Block: 256 threads (4 waves), TM=64 edges.
// LDS: sA (16 KB, phase 1-2) is aliased into the low half of sH (32 KB,
// phase 3+). Race-free: two __syncthreads separate the last sA read (GEMM1)
// from the first sH write. Union keeps LDS/block ~36 KB -> 4 blocks/CU.
// ---------------------------------------------------------------------------
__global__ __launch_bounds__(THREADS, 4) void fused_edge_kernel(
    const float* __restrict__ edges, const int* __restrict__ eidx,
    const float* __restrict__ ln1_g, const float* __restrict__ ln1_b,
    const float* __restrict__ b1,
    const float* __restrict__ ln2_g, const float* __restrict__ ln2_b,
    const float* __restrict__ b2,
    const float* __restrict__ wg, const float* __restrict__ bg,
    const float* __restrict__ bo,
    const u16* __restrict__ pw1, const u16* __restrict__ pw2,
    const u16* __restrict__ pwo,
    float* __restrict__ out, int E)
{
    __shared__ u16 sH[TM * H];          // 32 KB; low 16 KB doubles as sA
    __shared__ float sRedS[4][TM];
    __shared__ float sRedQ[4][TM];
    __shared__ float sMu[TM], sRs[TM], sGate[TM];
    __shared__ int   sIdx[TM];
    u16* sA = sH;                       // alias (see header comment)

    const int t    = threadIdx.x;
    const int lane = t & 63;
    const int wave = t >> 6;
    const int lr   = lane & 15;         // tile row/col within 16
    const int lg   = lane >> 4;         // k-group / row-quad id
    const int e0   = blockIdx.x * TM;

    if (t < TM) sIdx[t] = (e0 + t < E) ? eidx[e0 + t] : 0;

    // ---------------- Phase 1: load edges + LN1 -> sA (bf16, swizzled) ------
    {
        const int row = t >> 2;          // 0..63
        const int q   = t & 3;           // quarter of the row (32 cols)
        const int er  = min(e0 + row, E - 1);
        const float* src = edges + (size_t)er * D + q * 32;
        float x[32];
        #pragma unroll
        for (int i = 0; i < 8; ++i) {
            float4 v = reinterpret_cast<const float4*>(src)[i];
            x[i*4+0]=v.x; x[i*4+1]=v.y; x[i*4+2]=v.z; x[i*4+3]=v.w;
        }
        float s = 0.f, sq = 0.f;
        #pragma unroll
        for (int i = 0; i < 32; ++i) { s += x[i]; sq += x[i]*x[i]; }
        s  += __shfl_xor(s, 1);  s  += __shfl_xor(s, 2);
        sq += __shfl_xor(sq, 1); sq += __shfl_xor(sq, 2);
        const float mu  = s * (1.0f / D);
        const float var = sq * (1.0f / D) - mu * mu;
        const float rs  = rsqrtf(var + LN_EPS);
        #pragma unroll
        for (int i = 0; i < 4; ++i) {
            u32 p[4];
            #pragma unroll
            for (int j = 0; j < 4; ++j) {
                int c0 = q*32 + i*8 + j*2;
                float y0 = (x[i*8+j*2+0] - mu) * rs * ln1_g[c0+0] + ln1_b[c0+0];
                float y1 = (x[i*8+j*2+1] - mu) * rs * ln1_g[c0+1] + ln1_b[c0+1];
                p[j] = f2bf(y0) | (f2bf(y1) << 16);
            }
            int idx = (row * D + q*32 + i*8) ^ ((row & 7) << 3);
            *reinterpret_cast<uint4*>(&sA[idx]) = uint4{p[0], p[1], p[2], p[3]};
        }
    }
    __syncthreads();

    // ---------------- Phase 2: GEMM1  [64x128] x [128x256] ------------------
    f32x4 acc[4][4];
    #pragma unroll
    for (int a = 0; a < 4; ++a)
        #pragma unroll
        for (int b = 0; b < 4; ++b) acc[a][b] = f32x4{0.f,0.f,0.f,0.f};

    #pragma unroll
    for (int ks = 0; ks < 4; ++ks) {                 // k0 = ks*32
        bf16x8 af[4];
        #pragma unroll
        for (int mt = 0; mt < 4; ++mt) {
            int row = mt*16 + lr;
            int idx = (row * D + ks*32 + lg*8) ^ ((row & 7) << 3);
            af[mt] = *reinterpret_cast<const bf16x8*>(&sA[idx]);
        }
        bf16x8 bv[4];
        #pragma unroll
        for (int nt = 0; nt < 4; ++nt) {
            int ctile = wave*4 + nt;                 // col tile (of 16)
            int blk = ctile * 4 + ks;                // * (128/32)
            bv[nt] = *reinterpret_cast<const bf16x8*>(pw1 + blk*512 + lane*8);
        }
        #pragma unroll
        for (int mt = 0; mt < 4; ++mt)
            #pragma unroll
            for (int nt = 0; nt < 4; ++nt)
                acc[mt][nt] = __builtin_amdgcn_mfma_f32_16x16x32_bf16(af[mt], bv[nt], acc[mt][nt], 0, 0, 0);
    }

    // ---------------- Phase 3: +b1, ELU, LN2 partials -----------------------
    float b1v[4];
    #pragma unroll
    for (int nt = 0; nt < 4; ++nt) b1v[nt] = b1[wave*64 + nt*16 + lr];
    float ps[4][4], pq[4][4];                        // [mt][r]
    #pragma unroll
    for (int mt = 0; mt < 4; ++mt)
        #pragma unroll
        for (int r = 0; r < 4; ++r) { ps[mt][r] = 0.f; pq[mt][r] = 0.f; }
    #pragma unroll
    for (int mt = 0; mt < 4; ++mt)
        #pragma unroll
        for (int nt = 0; nt < 4; ++nt)
            #pragma unroll
            for (int r = 0; r < 4; ++r) {
                float x = acc[mt][nt][r] + b1v[nt];
                x = x > 0.f ? x : (__expf(x) - 1.f);     // ELU
                acc[mt][nt][r] = x;
                ps[mt][r] += x;
                pq[mt][r] += x * x;
            }
    #pragma unroll
    for (int mt = 0; mt < 4; ++mt)
        #pragma unroll
        for (int r = 0; r < 4; ++r) {
            float s = ps[mt][r], q = pq[mt][r];
            s += __shfl_xor(s, 1); s += __shfl_xor(s, 2); s += __shfl_xor(s, 4); s += __shfl_xor(s, 8);
            q += __shfl_xor(q, 1); q += __shfl_xor(q, 2); q += __shfl_xor(q, 4); q += __shfl_xor(q, 8);
            ps[mt][r] = s; pq[mt][r] = q;
        }
    if (lr == 0) {
        #pragma unroll
        for (int mt = 0; mt < 4; ++mt)
            #pragma unroll
            for (int r = 0; r < 4; ++r) {
                int row = mt*16 + lg*4 + r;
                sRedS[wave][row] = ps[mt][r];
                sRedQ[wave][row] = pq[mt][r];
            }
    }
    __syncthreads();
    if (t < TM) {
        float S = sRedS[0][t] + sRedS[1][t] + sRedS[2][t] + sRedS[3][t];
        float Q = sRedQ[0][t] + sRedQ[1][t] + sRedQ[2][t] + sRedQ[3][t];
        float mu  = S * (1.0f / H);
        float var = Q * (1.0f / H) - mu * mu;
        sMu[t] = mu;
        sRs[t] = rsqrtf(var + LN_EPS);
    }
    __syncthreads();

    // write LN2 output (bf16, swizzled) into sH  (overwrites dead sA alias)
    {
        float g2v[4], bt2[4];
        #pragma unroll
        for (int nt = 0; nt < 4; ++nt) {
            g2v[nt] = ln2_g[wave*64 + nt*16 + lr];
            bt2[nt] = ln2_b[wave*64 + nt*16 + lr];
        }
        #pragma unroll
        for (int mt = 0; mt < 4; ++mt)
            #pragma unroll
            for (int r = 0; r < 4; ++r) {
                int row = mt*16 + lg*4 + r;
                float mu = sMu[row], rs = sRs[row];
                #pragma unroll
                for (int nt = 0; nt < 4; ++nt) {
                    int col = wave*64 + nt*16 + lr;
                    float h = (acc[mt][nt][r] - mu) * rs * g2v[nt] + bt2[nt];
                    int idx = (row * H + col) ^ ((row & 7) << 3);
                    sH[idx] = (u16)f2bf(h);
                }
            }
    }
    __syncthreads();

    // ---------------- Phase 4: GEMM2  [64x256] x [256x256] ------------------
    #pragma unroll
    for (int a = 0; a < 4; ++a)
        #pragma unroll
        for (int b = 0; b < 4; ++b) acc[a][b] = f32x4{0.f,0.f,0.f,0.f};

    #pragma unroll
    for (int ks = 0; ks < 8; ++ks) {
        bf16x8 af[4];
        #pragma unroll
        for (int mt = 0; mt < 4; ++mt) {
            int row = mt*16 + lr;
            int idx = (row * H + ks*32 + lg*8) ^ ((row & 7) << 3);
            af[mt] = *reinterpret_cast<const bf16x8*>(&sH[idx]);
        }
        bf16x8 bv[4];
        #pragma unroll
        for (int nt = 0; nt < 4; ++nt) {
            int ctile = wave*4 + nt;
            int blk = ctile * 8 + ks;                // * (256/32)
            bv[nt] = *reinterpret_cast<const bf16x8*>(pw2 + blk*512 + lane*8);
        }
        #pragma unroll
        for (int mt = 0; mt < 4; ++mt)
            #pragma unroll
            for (int nt = 0; nt < 4; ++nt)
                acc[mt][nt] = __builtin_amdgcn_mfma_f32_16x16x32_bf16(af[mt], bv[nt], acc[mt][nt], 0, 0, 0);
    }

    // ---------------- Phase 5: +b2, gate partials, h2 -> sH -----------------
    float b2v[4], wgv[4];
    #pragma unroll
    for (int nt = 0; nt < 4; ++nt) {
        b2v[nt] = b2[wave*64 + nt*16 + lr];
        wgv[nt] = wg[wave*64 + nt*16 + lr];
    }
    float pg[4][4];
    #pragma unroll
    for (int mt = 0; mt < 4; ++mt)
        #pragma unroll
        for (int r = 0; r < 4; ++r) pg[mt][r] = 0.f;
    #pragma unroll
    for (int mt = 0; mt < 4; ++mt)
        #pragma unroll
        for (int nt = 0; nt < 4; ++nt)
            #pragma unroll
            for (int r = 0; r < 4; ++r) {
                float h2 = acc[mt][nt][r] + b2v[nt];
                acc[mt][nt][r] = h2;
                pg[mt][r] += h2 * wgv[nt];
            }
    #pragma unroll
    for (int mt = 0; mt < 4; ++mt)
        #pragma unroll
        for (int r = 0; r < 4; ++r) {
            float s = pg[mt][r];
            s += __shfl_xor(s, 1); s += __shfl_xor(s, 2); s += __shfl_xor(s, 4); s += __shfl_xor(s, 8);
            pg[mt][r] = s;
        }
    __syncthreads();                                  // all GEMM2 sH reads done
    #pragma unroll
    for (int mt = 0; mt < 4; ++mt)
        #pragma unroll
        for (int r = 0; r < 4; ++r) {
            int row = mt*16 + lg*4 + r;
            #pragma unroll
            for (int nt = 0; nt < 4; ++nt) {
                int col = wave*64 + nt*16 + lr;
                int idx = (row * H + col) ^ ((row & 7) << 3);
                sH[idx] = (u16)f2bf(acc[mt][nt][r]);
            }
        }
    if (lr == 0) {
        #pragma unroll
        for (int mt = 0; mt < 4; ++mt)
            #pragma unroll
            for (int r = 0; r < 4; ++r)
                sRedS[wave][mt*16 + lg*4 + r] = pg[mt][r];
    }
    __syncthreads();
    if (t < TM) {
        float z = sRedS[0][t] + sRedS[1][t] + sRedS[2][t] + sRedS[3][t] + bg[0];
        sGate[t] = 1.0f / (1.0f + __expf(-z));
    }
    __syncthreads();

    // ---------------- Phase 6: GEMM3  [64x256] x [256x128], scatter ---------
    f32x4 acc3[4][2];
    #pragma unroll
    for (int a = 0; a < 4; ++a)
        #pragma unroll
        for (int b = 0; b < 2; ++b) acc3[a][b] = f32x4{0.f,0.f,0.f,0.f};

    #pragma unroll
    for (int ks = 0; ks < 8; ++ks) {
        bf16x8 af[4];
        #pragma unroll
        for (int mt = 0; mt < 4; ++mt) {
            int row = mt*16 + lr;
            int idx = (row * H + ks*32 + lg*8) ^ ((row & 7) << 3);
            af[mt] = *reinterpret_cast<const bf16x8*>(&sH[idx]);
        }
        bf16x8 bv[2];
        #pragma unroll
        for (int nt = 0; nt < 2; ++nt) {
            int ctile = wave*2 + nt;                 // 8 col tiles over N=128
            int blk = ctile * 8 + ks;
            bv[nt] = *reinterpret_cast<const bf16x8*>(pwo + blk*512 + lane*8);
        }
        #pragma unroll
        for (int mt = 0; mt < 4; ++mt)
            #pragma unroll
            for (int nt = 0; nt < 2; ++nt)
                acc3[mt][nt] = __builtin_amdgcn_mfma_f32_16x16x32_bf16(af[mt], bv[nt], acc3[mt][nt], 0, 0, 0);
    }

    float bov[2];
    #pragma unroll
    for (int nt = 0; nt < 2; ++nt) bov[nt] = bo[wave*32 + nt*16 + lr];
    #pragma unroll
    for (int mt = 0; mt < 4; ++mt)
        #pragma unroll
        for (int r = 0; r < 4; ++r) {
            int row = mt*16 + lg*4 + r;
            if (e0 + row < E) {
                int node = sIdx[row];
                float gt = sGate[row];
                float* dst = out + (size_t)node * D;
                #pragma unroll
                for (int nt = 0; nt < 2; ++nt) {
                    int col = wave*32 + nt*16 + lr;
                    float v = (acc3[mt][nt][r] + bov[nt]) * gt;
                    unsafeAtomicAdd(dst + col, v);
                }
            }
        }
}

// ---------------------------------------------------------------------------
extern "C" void kernel_launch(void* const* d_in, const int* in_sizes, int n_in,
                              void* d_out, int out_size, void* d_ws, size_t ws_size,
                              hipStream_t stream) {
    const float* edges = (const float*)d_in[0];
    const int*   eidx  = (const int*)d_in[1];
    // d_in[2] = num_nodes (scalar) — out_size already encodes N*D
    const float* ln1_g = (const float*)d_in[3];
    const float* ln1_b = (const float*)d_in[4];
    const float* w1    = (const float*)d_in[5];
    const float* b1    = (const float*)d_in[6];
    const float* ln2_g = (const float*)d_in[7];
    const float* ln2_b = (const float*)d_in[8];
    const float* w2    = (const float*)d_in[9];
    const float* b2    = (const float*)d_in[10];
    const float* wg    = (const float*)d_in[11];
    const float* bg    = (const float*)d_in[12];
    const float* wo    = (const float*)d_in[13];
    const float* bo    = (const float*)d_in[14];
    float* out = (float*)d_out;
    const int E = in_sizes[0] / D;

    u16* pw1 = (u16*)d_ws;          // 32768 bf16
    u16* pw2 = pw1 + 32768;         // 65536 bf16
    u16* pwo = pw1 + 98304;         // 32768 bf16

    pack_weights<<<512, 256, 0, stream>>>(w1, w2, wo, pw1);
    int n4 = out_size / 4;
    zero_out_kernel<<<(n4 + 255) / 256, 256, 0, stream>>>((float4*)d_out, n4);
    fused_edge_kernel<<<(E + TM - 1) / TM, THREADS, 0, stream>>>(
        edges, eidx, ln1_g, ln1_b, b1, ln2_g, ln2_b, b2, wg, bg, bo,
        pw1, pw2, pwo, out, E);
}

// Round 3
// 486.392 us; speedup vs baseline: 1.4893x; 1.4893x over previous
//
#include <hip/hip_runtime.h>
#include <hip/hip_bf16.h>

typedef unsigned short u16;
typedef unsigned int u32;
typedef __bf16 bf16x8 __attribute__((ext_vector_type(8)));
typedef float f32x4 __attribute__((ext_vector_type(4)));

#define D 128
#define H 256
#define TM 64
#define THREADS 256
#define LN_EPS 1e-5f

__device__ __forceinline__ u32 f2bf(float f) {
    union { float f; u32 u; } v; v.f = f;
    return (v.u + 0x7FFFu + ((v.u >> 16) & 1u)) >> 16;   // RNE, low 16 bits valid
}

// ---------------------------------------------------------------------------
// Pack w1 [128x256], w2 [256x256], wo [256x128] (f32 row-major, K x N) into
// bf16 MFMA-fragment-contiguous blocks:
//   block b (per (coltile n0=16, ktile k0=32)): 512 bf16, layout
//   out[b*512 + l*8 + i] = W[(k0 + (l>>4)*8 + i) * N + n0 + (l&15)]
//   block id: b = (n0/16)*(K/32) + (k0/32)
// ---------------------------------------------------------------------------
__global__ void pack_weights(const float* __restrict__ w1,
                             const float* __restrict__ w2,
                             const float* __restrict__ wo,
                             u16* __restrict__ pw) {
    int tid = blockIdx.x * blockDim.x + threadIdx.x;
    const float* W; int K, NN, local;
    if (tid < 32768)       { W = w1; K = 128; NN = 256; local = tid; }
    else if (tid < 98304)  { W = w2; K = 256; NN = 256; local = tid - 32768; }
    else if (tid < 131072) { W = wo; K = 256; NN = 128; local = tid - 98304; }
    else return;
    int b = local >> 9, within = local & 511;
    int l = within >> 3, i = within & 7;
    int nbk = K >> 5;
    int n0 = (b / nbk) << 4, k0 = (b % nbk) << 5;
    int k = k0 + ((l >> 4) << 3) + i;
    int n = n0 + (l & 15);
    pw[tid] = (u16)f2bf(W[k * NN + n]);
}

__global__ void zero_out_kernel(float4* __restrict__ out, int n4) {
    int i = blockIdx.x * blockDim.x + threadIdx.x;
    if (i < n4) out[i] = float4{0.f, 0.f, 0.f, 0.f};
}

// ---------------------------------------------------------------------------
// Fused: LN1 -> GEMM1(+b1,ELU) -> LN2 -> GEMM2(+b2) -> gate -> GEMM3(+bo,*gate)
//        -> atomic scatter-add to out[node]
// Block: 256 threads (4 waves), TM=64 edges.
// LDS: sA (16 KB, phase 1-2) aliased into low half of sH (32 KB, phase 3+);
// race-free (two __syncthreads between last sA read and first sH write).
// __launch_bounds__(256,2): VGPR budget 256 -> compiler picks ~124, NO SPILL.
// (256,4) forced 64 VGPR and spilled ~2 GB/dispatch to scratch — R2 lesson.
// Occupancy = min(LDS 4 blocks/CU, VGPR 124<=128 -> 4 waves/SIMD) = 16 w/CU.
// ---------------------------------------------------------------------------
__global__ __launch_bounds__(THREADS, 2) void fused_edge_kernel(
    const float* __restrict__ edges, const int* __restrict__ eidx,
    const float* __restrict__ ln1_g, const float* __restrict__ ln1_b,
    const float* __restrict__ b1,
    const float* __restrict__ ln2_g, const float* __restrict__ ln2_b,
    const float* __restrict__ b2,
    const float* __restrict__ wg, const float* __restrict__ bg,
    const float* __restrict__ bo,
    const u16* __restrict__ pw1, const u16* __restrict__ pw2,
    const u16* __restrict__ pwo,
    float* __restrict__ out, int E)
{
    __shared__ u16 sH[TM * H];          // 32 KB; low 16 KB doubles as sA
    __shared__ float sRedS[4][TM];
    __shared__ float sRedQ[4][TM];
    __shared__ float sMu[TM], sRs[TM], sGate[TM];
    __shared__ int   sIdx[TM];
    u16* sA = sH;                       // alias (see header comment)

    const int t    = threadIdx.x;
    const int lane = t & 63;
    const int wave = t >> 6;
    const int lr   = lane & 15;         // tile row/col within 16
    const int lg   = lane >> 4;         // k-group / row-quad id
    const int e0   = blockIdx.x * TM;

    if (t < TM) sIdx[t] = (e0 + t < E) ? eidx[e0 + t] : 0;

    // ---------------- Phase 1: load edges + LN1 -> sA (bf16, swizzled) ------
    {
        const int row = t >> 2;          // 0..63
        const int q   = t & 3;           // quarter of the row (32 cols)
        const int er  = min(e0 + row, E - 1);
        const float* src = edges + (size_t)er * D + q * 32;
        float x[32];
        #pragma unroll
        for (int i = 0; i < 8; ++i) {
            float4 v = reinterpret_cast<const float4*>(src)[i];
            x[i*4+0]=v.x; x[i*4+1]=v.y; x[i*4+2]=v.z; x[i*4+3]=v.w;
        }
        float s = 0.f, sq = 0.f;
        #pragma unroll
        for (int i = 0; i < 32; ++i) { s += x[i]; sq += x[i]*x[i]; }
        s  += __shfl_xor(s, 1);  s  += __shfl_xor(s, 2);
        sq += __shfl_xor(sq, 1); sq += __shfl_xor(sq, 2);
        const float mu  = s * (1.0f / D);
        const float var = sq * (1.0f / D) - mu * mu;
        const float rs  = rsqrtf(var + LN_EPS);
        #pragma unroll
        for (int i = 0; i < 4; ++i) {
            u32 p[4];
            #pragma unroll
            for (int j = 0; j < 4; ++j) {
                int c0 = q*32 + i*8 + j*2;
                float y0 = (x[i*8+j*2+0] - mu) * rs * ln1_g[c0+0] + ln1_b[c0+0];
                float y1 = (x[i*8+j*2+1] - mu) * rs * ln1_g[c0+1] + ln1_b[c0+1];
                p[j] = f2bf(y0) | (f2bf(y1) << 16);
            }
            int idx = (row * D + q*32 + i*8) ^ ((row & 7) << 3);
            *reinterpret_cast<uint4*>(&sA[idx]) = uint4{p[0], p[1], p[2], p[3]};
        }
    }
    __syncthreads();

    // ---------------- Phase 2: GEMM1  [64x128] x [128x256] ------------------
    f32x4 acc[4][4];
    #pragma unroll
    for (int a = 0; a < 4; ++a)
        #pragma unroll
        for (int b = 0; b < 4; ++b) acc[a][b] = f32x4{0.f,0.f,0.f,0.f};

    #pragma unroll
    for (int ks = 0; ks < 4; ++ks) {                 // k0 = ks*32
        bf16x8 af[4];
        #pragma unroll
        for (int mt = 0; mt < 4; ++mt) {
            int row = mt*16 + lr;
            int idx = (row * D + ks*32 + lg*8) ^ ((row & 7) << 3);
            af[mt] = *reinterpret_cast<const bf16x8*>(&sA[idx]);
        }
        bf16x8 bv[4];
        #pragma unroll
        for (int nt = 0; nt < 4; ++nt) {
            int ctile = wave*4 + nt;                 // col tile (of 16)
            int blk = ctile * 4 + ks;                // * (128/32)
            bv[nt] = *reinterpret_cast<const bf16x8*>(pw1 + blk*512 + lane*8);
        }
        #pragma unroll
        for (int mt = 0; mt < 4; ++mt)
            #pragma unroll
            for (int nt = 0; nt < 4; ++nt)
                acc[mt][nt] = __builtin_amdgcn_mfma_f32_16x16x32_bf16(af[mt], bv[nt], acc[mt][nt], 0, 0, 0);
    }

    // ---------------- Phase 3: +b1, ELU, LN2 partials -----------------------
    float b1v[4];
    #pragma unroll
    for (int nt = 0; nt < 4; ++nt) b1v[nt] = b1[wave*64 + nt*16 + lr];
    float ps[4][4], pq[4][4];                        // [mt][r]
    #pragma unroll
    for (int mt = 0; mt < 4; ++mt)
        #pragma unroll
        for (int r = 0; r < 4; ++r) { ps[mt][r] = 0.f; pq[mt][r] = 0.f; }
    #pragma unroll
    for (int mt = 0; mt < 4; ++mt)
        #pragma unroll
        for (int nt = 0; nt < 4; ++nt)
            #pragma unroll
            for (int r = 0; r < 4; ++r) {
                float x = acc[mt][nt][r] + b1v[nt];
                x = x > 0.f ? x : (__expf(x) - 1.f);     // ELU
                acc[mt][nt][r] = x;
                ps[mt][r] += x;
                pq[mt][r] += x * x;
            }
    #pragma unroll
    for (int mt = 0; mt < 4; ++mt)
        #pragma unroll
        for (int r = 0; r < 4; ++r) {
            float s = ps[mt][r], q = pq[mt][r];
            s += __shfl_xor(s, 1); s += __shfl_xor(s, 2); s += __shfl_xor(s, 4); s += __shfl_xor(s, 8);
            q += __shfl_xor(q, 1); q += __shfl_xor(q, 2); q += __shfl_xor(q, 4); q += __shfl_xor(q, 8);
            ps[mt][r] = s; pq[mt][r] = q;
        }
    if (lr == 0) {
        #pragma unroll
        for (int mt = 0; mt < 4; ++mt)
            #pragma unroll
            for (int r = 0; r < 4; ++r) {
                int row = mt*16 + lg*4 + r;
                sRedS[wave][row] = ps[mt][r];
                sRedQ[wave][row] = pq[mt][r];
            }
    }
    __syncthreads();
    if (t < TM) {
        float S = sRedS[0][t] + sRedS[1][t] + sRedS[2][t] + sRedS[3][t];
        float Q = sRedQ[0][t] + sRedQ[1][t] + sRedQ[2][t] + sRedQ[3][t];
        float mu  = S * (1.0f / H);
        float var = Q * (1.0f / H) - mu * mu;
        sMu[t] = mu;
        sRs[t] = rsqrtf(var + LN_EPS);
    }
    __syncthreads();

    // write LN2 output (bf16, swizzled) into sH  (overwrites dead sA alias)
    {
        float g2v[4], bt2[4];
        #pragma unroll
        for (int nt = 0; nt < 4; ++nt) {
            g2v[nt] = ln2_g[wave*64 + nt*16 + lr];
            bt2[nt] = ln2_b[wave*64 + nt*16 + lr];
        }
        #pragma unroll
        for (int mt = 0; mt < 4; ++mt)
            #pragma unroll
            for (int r = 0; r < 4; ++r) {
                int row = mt*16 + lg*4 + r;
                float mu = sMu[row], rs = sRs[row];
                #pragma unroll
                for (int nt = 0; nt < 4; ++nt) {
                    int col = wave*64 + nt*16 + lr;
                    float h = (acc[mt][nt][r] - mu) * rs * g2v[nt] + bt2[nt];
                    int idx = (row * H + col) ^ ((row & 7) << 3);
                    sH[idx] = (u16)f2bf(h);
                }
            }
    }
    __syncthreads();

    // ---------------- Phase 4: GEMM2  [64x256] x [256x256] ------------------
    #pragma unroll
    for (int a = 0; a < 4; ++a)
        #pragma unroll
        for (int b = 0; b < 4; ++b) acc[a][b] = f32x4{0.f,0.f,0.f,0.f};

    #pragma unroll
    for (int ks = 0; ks < 8; ++ks) {
        bf16x8 af[4];
        #pragma unroll
        for (int mt = 0; mt < 4; ++mt) {
            int row = mt*16 + lr;
            int idx = (row * H + ks*32 + lg*8) ^ ((row & 7) << 3);
            af[mt] = *reinterpret_cast<const bf16x8*>(&sH[idx]);
        }
        bf16x8 bv[4];
        #pragma unroll
        for (int nt = 0; nt < 4; ++nt) {
            int ctile = wave*4 + nt;
            int blk = ctile * 8 + ks;                // * (256/32)
            bv[nt] = *reinterpret_cast<const bf16x8*>(pw2 + blk*512 + lane*8);
        }
        #pragma unroll
        for (int mt = 0; mt < 4; ++mt)
            #pragma unroll
            for (int nt = 0; nt < 4; ++nt)
                acc[mt][nt] = __builtin_amdgcn_mfma_f32_16x16x32_bf16(af[mt], bv[nt], acc[mt][nt], 0, 0, 0);
    }

    // ---------------- Phase 5: +b2, gate partials, h2 -> sH -----------------
    float b2v[4], wgv[4];
    #pragma unroll
    for (int nt = 0; nt < 4; ++nt) {
        b2v[nt] = b2[wave*64 + nt*16 + lr];
        wgv[nt] = wg[wave*64 + nt*16 + lr];
    }
    float pg[4][4];
    #pragma unroll
    for (int mt = 0; mt < 4; ++mt)
        #pragma unroll
        for (int r = 0; r < 4; ++r) pg[mt][r] = 0.f;
    #pragma unroll
    for (int mt = 0; mt < 4; ++mt)
        #pragma unroll
        for (int nt = 0; nt < 4; ++nt)
            #pragma unroll
            for (int r = 0; r < 4; ++r) {
                float h2 = acc[mt][nt][r] + b2v[nt];
                acc[mt][nt][r] = h2;
                pg[mt][r] += h2 * wgv[nt];
            }
    #pragma unroll
    for (int mt = 0; mt < 4; ++mt)
        #pragma unroll
        for (int r = 0; r < 4; ++r) {
            float s = pg[mt][r];
            s += __shfl_xor(s, 1); s += __shfl_xor(s, 2); s += __shfl_xor(s, 4); s += __shfl_xor(s, 8);
            pg[mt][r] = s;
        }
    __syncthreads();                                  // all GEMM2 sH reads done
    #pragma unroll
    for (int mt = 0; mt < 4; ++mt)
        #pragma unroll
        for (int r = 0; r < 4; ++r) {
            int row = mt*16 + lg*4 + r;
            #pragma unroll
            for (int nt = 0; nt < 4; ++nt) {
                int col = wave*64 + nt*16 + lr;
                int idx = (row * H + col) ^ ((row & 7) << 3);
                sH[idx] = (u16)f2bf(acc[mt][nt][r]);
            }
        }
    if (lr == 0) {
        #pragma unroll
        for (int mt = 0; mt < 4; ++mt)
            #pragma unroll
            for (int r = 0; r < 4; ++r)
                sRedS[wave][mt*16 + lg*4 + r] = pg[mt][r];
    }
    __syncthreads();
    if (t < TM) {
        float z = sRedS[0][t] + sRedS[1][t] + sRedS[2][t] + sRedS[3][t] + bg[0];
        sGate[t] = 1.0f / (1.0f + __expf(-z));
    }
    __syncthreads();

    // ---------------- Phase 6: GEMM3  [64x256] x [256x128], scatter ---------
    f32x4 acc3[4][2];
    #pragma unroll
    for (int a = 0; a < 4; ++a)
        #pragma unroll
        for (int b = 0; b < 2; ++b) acc3[a][b] = f32x4{0.f,0.f,0.f,0.f};

    #pragma unroll
    for (int ks = 0; ks < 8; ++ks) {
        bf16x8 af[4];
        #pragma unroll
        for (int mt = 0; mt < 4; ++mt) {
            int row = mt*16 + lr;
            int idx = (row * H + ks*32 + lg*8) ^ ((row & 7) << 3);
            af[mt] = *reinterpret_cast<const bf16x8*>(&sH[idx]);
        }
        bf16x8 bv[2];
        #pragma unroll
        for (int nt = 0; nt < 2; ++nt) {
            int ctile = wave*2 + nt;                 // 8 col tiles over N=128
            int blk = ctile * 8 + ks;
            bv[nt] = *reinterpret_cast<const bf16x8*>(pwo + blk*512 + lane*8);
        }
        #pragma unroll
        for (int mt = 0; mt < 4; ++mt)
            #pragma unroll
            for (int nt = 0; nt < 2; ++nt)
                acc3[mt][nt] = __builtin_amdgcn_mfma_f32_16x16x32_bf16(af[mt], bv[nt], acc3[mt][nt], 0, 0, 0);
    }

    float bov[2];
    #pragma unroll
    for (int nt = 0; nt < 2; ++nt) bov[nt] = bo[wave*32 + nt*16 + lr];
    #pragma unroll
    for (int mt = 0; mt < 4; ++mt)
        #pragma unroll
        for (int r = 0; r < 4; ++r) {
            int row = mt*16 + lg*4 + r;
            if (e0 + row < E) {
                int node = sIdx[row];
                float gt = sGate[row];
                float* dst = out + (size_t)node * D;
                #pragma unroll
                for (int nt = 0; nt < 2; ++nt) {
                    int col = wave*32 + nt*16 + lr;
                    float v = (acc3[mt][nt][r] + bov[nt]) * gt;
                    unsafeAtomicAdd(dst + col, v);
                }
            }
        }
}

// ---------------------------------------------------------------------------
extern "C" void kernel_launch(void* const* d_in, const int* in_sizes, int n_in,
                              void* d_out, int out_size, void* d_ws, size_t ws_size,
                              hipStream_t stream) {
    const float* edges = (const float*)d_in[0];
    const int*   eidx  = (const int*)d_in[1];
    // d_in[2] = num_nodes (scalar) — out_size already encodes N*D
    const float* ln1_g = (const float*)d_in[3];
    const float* ln1_b = (const float*)d_in[4];
    const float* w1    = (const float*)d_in[5];
    const float* b1    = (const float*)d_in[6];
    const float* ln2_g = (const float*)d_in[7];
    const float* ln2_b = (const float*)d_in[8];
    const float* w2    = (const float*)d_in[9];
    const float* b2    = (const float*)d_in[10];
    const float* wg    = (const float*)d_in[11];
    const float* bg    = (const float*)d_in[12];
    const float* wo    = (const float*)d_in[13];
    const float* bo    = (const float*)d_in[14];
    float* out = (float*)d_out;
    const int E = in_sizes[0] / D;

    u16* pw1 = (u16*)d_ws;          // 32768 bf16
    u16* pw2 = pw1 + 32768;         // 65536 bf16
    u16* pwo = pw1 + 98304;         // 32768 bf16

    pack_weights<<<512, 256, 0, stream>>>(w1, w2, wo, pw1);
    int n4 = out_size / 4;
    zero_out_kernel<<<(n4 + 255) / 256, 256, 0, stream>>>((float4*)d_out, n4);
    fused_edge_kernel<<<(E + TM - 1) / TM, THREADS, 0, stream>>>(
        edges, eidx, ln1_g, ln1_b, b1, ln2_g, ln2_b, b2, wg, bg, bo,
        pw1, pw2, pwo, out, E);
}

// Round 4
// 444.638 us; speedup vs baseline: 1.6292x; 1.0939x over previous
//
#include <hip/hip_runtime.h>
#include <hip/hip_bf16.h>

typedef unsigned short u16;
typedef unsigned int u32;
typedef __bf16 bf16x8 __attribute__((ext_vector_type(8)));
typedef float f32x4 __attribute__((ext_vector_type(4)));

#define D 128
#define H 256
#define TM 32
#define THREADS 256
#define LN_EPS 1e-5f

__device__ __forceinline__ u32 f2bf(float f) {
    union { float f; u32 u; } v; v.f = f;
    return (v.u + 0x7FFFu + ((v.u >> 16) & 1u)) >> 16;   // RNE, low 16 bits valid
}

// ---------------------------------------------------------------------------
// Pack w1 [128x256], w2 [256x256], wo [256x128] (f32 row-major, K x N) into
// bf16 MFMA-fragment-contiguous blocks:
//   block b (per (coltile n0=16, ktile k0=32)): 512 bf16, layout
//   out[b*512 + l*8 + i] = W[(k0 + (l>>4)*8 + i) * N + n0 + (l&15)]
//   block id: b = (n0/16)*(K/32) + (k0/32)
// ---------------------------------------------------------------------------
__global__ void pack_weights(const float* __restrict__ w1,
                             const float* __restrict__ w2,
                             const float* __restrict__ wo,
                             u16* __restrict__ pw) {
    int tid = blockIdx.x * blockDim.x + threadIdx.x;
    const float* W; int K, NN, local;
    if (tid < 32768)       { W = w1; K = 128; NN = 256; local = tid; }
    else if (tid < 98304)  { W = w2; K = 256; NN = 256; local = tid - 32768; }
    else if (tid < 131072) { W = wo; K = 256; NN = 128; local = tid - 98304; }
    else return;
    int b = local >> 9, within = local & 511;
    int l = within >> 3, i = within & 7;
    int nbk = K >> 5;
    int n0 = (b / nbk) << 4, k0 = (b % nbk) << 5;
    int k = k0 + ((l >> 4) << 3) + i;
    int n = n0 + (l & 15);
    pw[tid] = (u16)f2bf(W[k * NN + n]);
}

__global__ void zero_out_kernel(float4* __restrict__ out, int n4) {
    int i = blockIdx.x * blockDim.x + threadIdx.x;
    if (i < n4) out[i] = float4{0.f, 0.f, 0.f, 0.f};
}

// ---------------------------------------------------------------------------
// Fused: LN1 -> GEMM1(+b1,ELU) -> LN2 -> GEMM2(+b2) -> gate -> GEMM3(+bo,*gate)
//        -> atomic scatter-add to out[node]
// Block: 256 threads (4 waves), TM=32 edges. Each wave: 32 rows x 64 cols
// -> acc[2][4] (32 regs) instead of R1-R3's 64x64 acc[4][4] (64 regs).
// R3 lesson: combined VGPR+AGPR ~250/wave capped occupancy at 2 blocks/CU
// (23%) regardless of LDS. Smaller tile -> ~150 regs -> (256,3) cap (~170)
// is safe (R2 lesson: never cap below structural need -> 2GB spills).
// LDS: sA (8 KB) aliased into sH (16 KB); race-free (two __syncthreads
// between last sA read and first sH write). ~18 KB/block.
// ---------------------------------------------------------------------------
__global__ __launch_bounds__(THREADS, 3) void fused_edge_kernel(
    const float* __restrict__ edges, const int* __restrict__ eidx,
    const float* __restrict__ ln1_g, const float* __restrict__ ln1_b,
    const float* __restrict__ b1,
    const float* __restrict__ ln2_g, const float* __restrict__ ln2_b,
    const float* __restrict__ b2,
    const float* __restrict__ wg, const float* __restrict__ bg,
    const float* __restrict__ bo,
    const u16* __restrict__ pw1, const u16* __restrict__ pw2,
    const u16* __restrict__ pwo,
    float* __restrict__ out, int E)
{
    __shared__ u16 sH[TM * H];          // 16 KB; low 8 KB doubles as sA
    __shared__ float sRedS[4][TM];
    __shared__ float sRedQ[4][TM];
    __shared__ float sMu[TM], sRs[TM], sGate[TM];
    __shared__ int   sIdx[TM];
    u16* sA = sH;                       // alias (see header comment)

    const int t    = threadIdx.x;
    const int lane = t & 63;
    const int wave = t >> 6;
    const int lr   = lane & 15;         // tile row/col within 16
    const int lg   = lane >> 4;         // k-group / row-quad id
    const int e0   = blockIdx.x * TM;

    if (t < TM) sIdx[t] = (e0 + t < E) ? eidx[e0 + t] : 0;

    // ---------------- Phase 1: load edges + LN1 -> sA (bf16, swizzled) ------
    {
        const int row = t >> 3;          // 0..31
        const int c8  = t & 7;           // 16-col chunk of the row
        const int er  = min(e0 + row, E - 1);
        const float* src = edges + (size_t)er * D + c8 * 16;
        float x[16];
        #pragma unroll
        for (int i = 0; i < 4; ++i) {
            float4 v = reinterpret_cast<const float4*>(src)[i];
            x[i*4+0]=v.x; x[i*4+1]=v.y; x[i*4+2]=v.z; x[i*4+3]=v.w;
        }
        float s = 0.f, sq = 0.f;
        #pragma unroll
        for (int i = 0; i < 16; ++i) { s += x[i]; sq += x[i]*x[i]; }
        s  += __shfl_xor(s, 1);  s  += __shfl_xor(s, 2);  s  += __shfl_xor(s, 4);
        sq += __shfl_xor(sq, 1); sq += __shfl_xor(sq, 2); sq += __shfl_xor(sq, 4);
        const float mu  = s * (1.0f / D);
        const float var = sq * (1.0f / D) - mu * mu;
        const float rs  = rsqrtf(var + LN_EPS);
        #pragma unroll
        for (int i = 0; i < 2; ++i) {
            u32 p[4];
            #pragma unroll
            for (int j = 0; j < 4; ++j) {
                int c0 = c8*16 + i*8 + j*2;
                float y0 = (x[i*8+j*2+0] - mu) * rs * ln1_g[c0+0] + ln1_b[c0+0];
                float y1 = (x[i*8+j*2+1] - mu) * rs * ln1_g[c0+1] + ln1_b[c0+1];
                p[j] = f2bf(y0) | (f2bf(y1) << 16);
            }
            int idx = (row * D + c8*16 + i*8) ^ ((row & 7) << 3);
            *reinterpret_cast<uint4*>(&sA[idx]) = uint4{p[0], p[1], p[2], p[3]};
        }
    }
    __syncthreads();

    // ---------------- Phase 2: GEMM1  [32x128] x [128x256] ------------------
    f32x4 acc[2][4];
    #pragma unroll
    for (int a = 0; a < 2; ++a)
        #pragma unroll
        for (int b = 0; b < 4; ++b) acc[a][b] = f32x4{0.f,0.f,0.f,0.f};

    #pragma unroll
    for (int ks = 0; ks < 4; ++ks) {                 // k0 = ks*32
        bf16x8 af[2];
        #pragma unroll
        for (int mt = 0; mt < 2; ++mt) {
            int row = mt*16 + lr;
            int idx = (row * D + ks*32 + lg*8) ^ ((row & 7) << 3);
            af[mt] = *reinterpret_cast<const bf16x8*>(&sA[idx]);
        }
        bf16x8 bv[4];
        #pragma unroll
        for (int nt = 0; nt < 4; ++nt) {
            int ctile = wave*4 + nt;                 // col tile (of 16)
            int blk = ctile * 4 + ks;                // * (128/32)
            bv[nt] = *reinterpret_cast<const bf16x8*>(pw1 + blk*512 + lane*8);
        }
        #pragma unroll
        for (int mt = 0; mt < 2; ++mt)
            #pragma unroll
            for (int nt = 0; nt < 4; ++nt)
                acc[mt][nt] = __builtin_amdgcn_mfma_f32_16x16x32_bf16(af[mt], bv[nt], acc[mt][nt], 0, 0, 0);
    }

    // ---------------- Phase 3: +b1, ELU, LN2 partials -----------------------
    float b1v[4];
    #pragma unroll
    for (int nt = 0; nt < 4; ++nt) b1v[nt] = b1[wave*64 + nt*16 + lr];
    float ps[2][4], pq[2][4];                        // [mt][r]
    #pragma unroll
    for (int mt = 0; mt < 2; ++mt)
        #pragma unroll
        for (int r = 0; r < 4; ++r) { ps[mt][r] = 0.f; pq[mt][r] = 0.f; }
    #pragma unroll
    for (int mt = 0; mt < 2; ++mt)
        #pragma unroll
        for (int nt = 0; nt < 4; ++nt)
            #pragma unroll
            for (int r = 0; r < 4; ++r) {
                float x = acc[mt][nt][r] + b1v[nt];
                x = x > 0.f ? x : (__expf(x) - 1.f);     // ELU
                acc[mt][nt][r] = x;
                ps[mt][r] += x;
                pq[mt][r] += x * x;
            }
    #pragma unroll
    for (int mt = 0; mt < 2; ++mt)
        #pragma unroll
        for (int r = 0; r < 4; ++r) {
            float s = ps[mt][r], q = pq[mt][r];
            s += __shfl_xor(s, 1); s += __shfl_xor(s, 2); s += __shfl_xor(s, 4); s += __shfl_xor(s, 8);
            q += __shfl_xor(q, 1); q += __shfl_xor(q, 2); q += __shfl_xor(q, 4); q += __shfl_xor(q, 8);
            ps[mt][r] = s; pq[mt][r] = q;
        }
    if (lr == 0) {
        #pragma unroll
        for (int mt = 0; mt < 2; ++mt)
            #pragma unroll
            for (int r = 0; r < 4; ++r) {
                int row = mt*16 + lg*4 + r;
                sRedS[wave][row] = ps[mt][r];
                sRedQ[wave][row] = pq[mt][r];
            }
    }
    __syncthreads();
    if (t < TM) {
        float S = sRedS[0][t] + sRedS[1][t] + sRedS[2][t] + sRedS[3][t];
        float Q = sRedQ[0][t] + sRedQ[1][t] + sRedQ[2][t] + sRedQ[3][t];
        float mu  = S * (1.0f / H);
        float var = Q * (1.0f / H) - mu * mu;
        sMu[t] = mu;
        sRs[t] = rsqrtf(var + LN_EPS);
    }
    __syncthreads();

    // write LN2 output (bf16, swizzled) into sH  (overwrites dead sA alias)
    {
        float g2v[4], bt2[4];
        #pragma unroll
        for (int nt = 0; nt < 4; ++nt) {
            g2v[nt] = ln2_g[wave*64 + nt*16 + lr];
            bt2[nt] = ln2_b[wave*64 + nt*16 + lr];
        }
        #pragma unroll
        for (int mt = 0; mt < 2; ++mt)
            #pragma unroll
            for (int r = 0; r < 4; ++r) {
                int row = mt*16 + lg*4 + r;
                float mu = sMu[row], rs = sRs[row];
                #pragma unroll
                for (int nt = 0; nt < 4; ++nt) {
                    int col = wave*64 + nt*16 + lr;
                    float h = (acc[mt][nt][r] - mu) * rs * g2v[nt] + bt2[nt];
                    int idx = (row * H + col) ^ ((row & 7) << 3);
                    sH[idx] = (u16)f2bf(h);
                }
            }
    }
    __syncthreads();

    // ---------------- Phase 4: GEMM2  [32x256] x [256x256] ------------------
    #pragma unroll
    for (int a = 0; a < 2; ++a)
        #pragma unroll
        for (int b = 0; b < 4; ++b) acc[a][b] = f32x4{0.f,0.f,0.f,0.f};

    #pragma unroll
    for (int ks = 0; ks < 8; ++ks) {
        bf16x8 af[2];
        #pragma unroll
        for (int mt = 0; mt < 2; ++mt) {
            int row = mt*16 + lr;
            int idx = (row * H + ks*32 + lg*8) ^ ((row & 7) << 3);
            af[mt] = *reinterpret_cast<const bf16x8*>(&sH[idx]);
        }
        bf16x8 bv[4];
        #pragma unroll
        for (int nt = 0; nt < 4; ++nt) {
            int ctile = wave*4 + nt;
            int blk = ctile * 8 + ks;                // * (256/32)
            bv[nt] = *reinterpret_cast<const bf16x8*>(pw2 + blk*512 + lane*8);
        }
        #pragma unroll
        for (int mt = 0; mt < 2; ++mt)
            #pragma unroll
            for (int nt = 0; nt < 4; ++nt)
                acc[mt][nt] = __builtin_amdgcn_mfma_f32_16x16x32_bf16(af[mt], bv[nt], acc[mt][nt], 0, 0, 0);
    }

    // ---------------- Phase 5: +b2, gate partials, h2 -> sH -----------------
    float b2v[4], wgv[4];
    #pragma unroll
    for (int nt = 0; nt < 4; ++nt) {
        b2v[nt] = b2[wave*64 + nt*16 + lr];
        wgv[nt] = wg[wave*64 + nt*16 + lr];
    }
    float pg[2][4];
    #pragma unroll
    for (int mt = 0; mt < 2; ++mt)
        #pragma unroll
        for (int r = 0; r < 4; ++r) pg[mt][r] = 0.f;
    #pragma unroll
    for (int mt = 0; mt < 2; ++mt)
        #pragma unroll
        for (int nt = 0; nt < 4; ++nt)
            #pragma unroll
            for (int r = 0; r < 4; ++r) {
                float h2 = acc[mt][nt][r] + b2v[nt];
                acc[mt][nt][r] = h2;
                pg[mt][r] += h2 * wgv[nt];
            }
    #pragma unroll
    for (int mt = 0; mt < 2; ++mt)
        #pragma unroll
        for (int r = 0; r < 4; ++r) {
            float s = pg[mt][r];
            s += __shfl_xor(s, 1); s += __shfl_xor(s, 2); s += __shfl_xor(s, 4); s += __shfl_xor(s, 8);
            pg[mt][r] = s;
        }
    __syncthreads();                                  // all GEMM2 sH reads done
    #pragma unroll
    for (int mt = 0; mt < 2; ++mt)
        #pragma unroll
        for (int r = 0; r < 4; ++r) {
            int row = mt*16 + lg*4 + r;
            #pragma unroll
            for (int nt = 0; nt < 4; ++nt) {
                int col = wave*64 + nt*16 + lr;
                int idx = (row * H + col) ^ ((row & 7) << 3);
                sH[idx] = (u16)f2bf(acc[mt][nt][r]);
            }
        }
    if (lr == 0) {
        #pragma unroll
        for (int mt = 0; mt < 2; ++mt)
            #pragma unroll
            for (int r = 0; r < 4; ++r)
                sRedS[wave][mt*16 + lg*4 + r] = pg[mt][r];
    }
    __syncthreads();
    if (t < TM) {
        float z = sRedS[0][t] + sRedS[1][t] + sRedS[2][t] + sRedS[3][t] + bg[0];
        sGate[t] = 1.0f / (1.0f + __expf(-z));
    }
    __syncthreads();

    // ---------------- Phase 6: GEMM3  [32x256] x [256x128], scatter ---------
    f32x4 acc3[2][2];
    #pragma unroll
    for (int a = 0; a < 2; ++a)
        #pragma unroll
        for (int b = 0; b < 2; ++b) acc3[a][b] = f32x4{0.f,0.f,0.f,0.f};

    #pragma unroll
    for (int ks = 0; ks < 8; ++ks) {
        bf16x8 af[2];
        #pragma unroll
        for (int mt = 0; mt < 2; ++mt) {
            int row = mt*16 + lr;
            int idx = (row * H + ks*32 + lg*8) ^ ((row & 7) << 3);
            af[mt] = *reinterpret_cast<const bf16x8*>(&sH[idx]);
        }
        bf16x8 bv[2];
        #pragma unroll
        for (int nt = 0; nt < 2; ++nt) {
            int ctile = wave*2 + nt;                 // 8 col tiles over N=128
            int blk = ctile * 8 + ks;
            bv[nt] = *reinterpret_cast<const bf16x8*>(pwo + blk*512 + lane*8);
        }
        #pragma unroll
        for (int mt = 0; mt < 2; ++mt)
            #pragma unroll
            for (int nt = 0; nt < 2; ++nt)
                acc3[mt][nt] = __builtin_amdgcn_mfma_f32_16x16x32_bf16(af[mt], bv[nt], acc3[mt][nt], 0, 0, 0);
    }

    float bov[2];
    #pragma unroll
    for (int nt = 0; nt < 2; ++nt) bov[nt] = bo[wave*32 + nt*16 + lr];
    #pragma unroll
    for (int mt = 0; mt < 2; ++mt)
        #pragma unroll
        for (int r = 0; r < 4; ++r) {
            int row = mt*16 + lg*4 + r;
            if (e0 + row < E) {
                int node = sIdx[row];
                float gt = sGate[row];
                float* dst = out + (size_t)node * D;
                #pragma unroll
                for (int nt = 0; nt < 2; ++nt) {
                    int col = wave*32 + nt*16 + lr;
                    float v = (acc3[mt][nt][r] + bov[nt]) * gt;
                    unsafeAtomicAdd(dst + col, v);
                }
            }
        }
}

// ---------------------------------------------------------------------------
extern "C" void kernel_launch(void* const* d_in, const int* in_sizes, int n_in,
                              void* d_out, int out_size, void* d_ws, size_t ws_size,
                              hipStream_t stream) {
    const float* edges = (const float*)d_in[0];
    const int*   eidx  = (const int*)d_in[1];
    // d_in[2] = num_nodes (scalar) — out_size already encodes N*D
    const float* ln1_g = (const float*)d_in[3];
    const float* ln1_b = (const float*)d_in[4];
    const float* w1    = (const float*)d_in[5];
    const float* b1    = (const float*)d_in[6];
    const float* ln2_g = (const float*)d_in[7];
    const float* ln2_b = (const float*)d_in[8];
    const float* w2    = (const float*)d_in[9];
    const float* b2    = (const float*)d_in[10];
    const float* wg    = (const float*)d_in[11];
    const float* bg    = (const float*)d_in[12];
    const float* wo    = (const float*)d_in[13];
    const float* bo    = (const float*)d_in[14];
    float* out = (float*)d_out;
    const int E = in_sizes[0] / D;

    u16* pw1 = (u16*)d_ws;          // 32768 bf16
    u16* pw2 = pw1 + 32768;         // 65536 bf16
    u16* pwo = pw1 + 98304;         // 32768 bf16

    pack_weights<<<512, 256, 0, stream>>>(w1, w2, wo, pw1);
    int n4 = out_size / 4;
    zero_out_kernel<<<(n4 + 255) / 256, 256, 0, stream>>>((float4*)d_out, n4);
    fused_edge_kernel<<<(E + TM - 1) / TM, THREADS, 0, stream>>>(
        edges, eidx, ln1_g, ln1_b, b1, ln2_g, ln2_b, b2, wg, bg, bo,
        pw1, pw2, pwo, out, E);
}